// Round 6
// baseline (18.907 us; speedup 1.0000x reference)
//
#include <hip/hip_runtime.h>
#include <hip/hip_bf16.h>

// Pooler ragged-mean: out[b,s,:] = mean(features[b, begins[b,s]:ends[b,s], :])
// B=8, T=4096, D=256, S=1024, MAX_W=32. Empty spans -> 0.
//
// R6: two-phase. Phase A: per-batch counting sort of spans by begin
// (16-row buckets) -> perm in d_ws. Phase B: pooling, one wave per span,
// 4 sorted-adjacent spans per block => block read footprint ~28 KB fits L1,
// the ~4x logical row duplication becomes L1 hits instead of L1 misses
// (R2-R5 plateau at ~14.5 us diagnosed as L1-miss/MSHR throughput bound).
// XCD swizzle keeps batch b pinned to XCD b (4 MB = one L2).

#define B_DIM 8
#define T_DIM 4096
#define D_DIM 256
#define S_DIM 1024
#define MAX_W 32
#define NXCD 8

typedef float vfloat4 __attribute__((ext_vector_type(4)));

__global__ __launch_bounds__(256) void sort_spans_kernel(
    const int* __restrict__ begins,   // [B, S]
    int*       __restrict__ perm)     // [B, S] out: local span idx sorted by begin
{
    const int b = blockIdx.x;
    const int t = threadIdx.x;  // 0..255

    __shared__ int hist[256];
    __shared__ int scanbuf[256];

    hist[t] = 0;
    __syncthreads();

    int key[4];
    #pragma unroll
    for (int k = 0; k < 4; ++k) {
        const int s = t * 4 + k;
        int bg = begins[b * S_DIM + s];
        bg = bg > 0 ? bg : 0;
        bg = bg < (T_DIM - 1) ? bg : (T_DIM - 1);
        key[k] = bg >> 4;                 // 16-row buckets -> 256 bins
        atomicAdd(&hist[key[k]], 1);
    }
    __syncthreads();

    // Hillis-Steele inclusive scan over 256 bins
    int own = hist[t];
    scanbuf[t] = own;
    __syncthreads();
    for (int off = 1; off < 256; off <<= 1) {
        const int add = (t >= off) ? scanbuf[t - off] : 0;
        __syncthreads();
        scanbuf[t] += add;
        __syncthreads();
    }
    hist[t] = scanbuf[t] - own;           // exclusive prefix = running offset
    __syncthreads();

    #pragma unroll
    for (int k = 0; k < 4; ++k) {
        const int s = t * 4 + k;
        const int pos = atomicAdd(&hist[key[k]], 1);
        perm[b * S_DIM + pos] = s;
    }
}

__global__ __launch_bounds__(256) void pooler_kernel(
    const float* __restrict__ features,   // [B, T, D]
    const int*   __restrict__ begins,     // [B, S]
    const int*   __restrict__ ends,       // [B, S]
    const int*   __restrict__ perm,       // [B, S] or unused
    const int                 use_perm,
    float*       __restrict__ out)        // [B, S, D]
{
    const int phys = blockIdx.x;
    const int lblk = (phys & (NXCD - 1)) * (2048 / NXCD) + (phys >> 3);

    const int slot = lblk * 4 + (threadIdx.x >> 6);  // [0, B*S)
    const int lane = threadIdx.x & 63;
    const int b = slot >> 10;                        // S_DIM = 1024

    const int span = use_perm ? (b * S_DIM + perm[slot]) : slot;

    int begin = begins[span];
    int end   = ends[span];
    begin = begin > 0 ? begin : 0;
    end   = end   > 0 ? end   : 0;
    end   = end   < T_DIM ? end : T_DIM;  // => begin+j <= T-1, clamp hoisted
    int w = end - begin;
    w = w < MAX_W ? w : MAX_W;

    vfloat4* outp = reinterpret_cast<vfloat4*>(out + (size_t)span * D_DIM) + lane;

    if (w <= 0) {
        vfloat4 z = {0.f, 0.f, 0.f, 0.f};
        __builtin_nontemporal_store(z, outp);
        return;
    }

    const vfloat4* p = reinterpret_cast<const vfloat4*>(
        features + (size_t)b * T_DIM * D_DIM + (size_t)begin * D_DIM) + lane;

    vfloat4 acc = {0.f, 0.f, 0.f, 0.f};
    #pragma unroll 8
    for (int j = 0; j < w; ++j) {
        acc += p[(size_t)j * (D_DIM / 4)];
    }

    const float inv = 1.0f / (float)w;
    vfloat4 r = acc * inv;
    __builtin_nontemporal_store(r, outp);
}

extern "C" void kernel_launch(void* const* d_in, const int* in_sizes, int n_in,
                              void* d_out, int out_size, void* d_ws, size_t ws_size,
                              hipStream_t stream) {
    const float* features = (const float*)d_in[0];
    const int*   begins   = (const int*)d_in[1];
    const int*   ends     = (const int*)d_in[2];
    float*       out      = (float*)d_out;

    const int n_spans = B_DIM * S_DIM;            // 8192
    const int blocks  = n_spans / 4;              // 4 spans (waves) per block

    int* perm = (int*)d_ws;
    const int use_perm = (ws_size >= (size_t)n_spans * sizeof(int)) ? 1 : 0;

    if (use_perm) {
        sort_spans_kernel<<<B_DIM, 256, 0, stream>>>(begins, perm);
    }
    pooler_kernel<<<blocks, 256, 0, stream>>>(features, begins, ends,
                                              perm, use_perm, out);
}